// Round 5
// baseline (296.814 us; speedup 1.0000x reference)
//
#include <hip/hip_runtime.h>
#include <hip/hip_bf16.h>
#include <stdint.h>

// DenseGraphAttentionHead N=8192, IN=512, OUT=256, ~50% dense int32 mask.
//
// Pipeline:
//   k_convert_w : W f32 -> bf16 chunked (16B chunk (kb,row) at kb*2048+row*8).
//   k_wh        : Wh = nodes@W^T + b (mfma 16x16x32 bf16) -> WhL chunked bf16
//                 (chunk (jb,n) at jb*2048+n*8), s1/s2 f32 from f32 acc.
//   k_mask      : int32 mask (268 MB, the irreducible HBM stream) -> bitmask
//                 bm[row][wj] (8.4 MB) via __ballot. Pure streaming kernel.
//   k_attn      : fused masked-softmax @ Wh on the BITMASK. Grid = 64
//                 row-tiles(BM=128) x 8 j-chunks(1024) = 512 blocks (2/CU,
//                 16 waves/CU). Block = 8 waves = 4 rowgroups(32 rows) x 2
//                 j-subchunks(512). Explicit 2-step register ping-pong for
//                 B-frags + mask/s2 (static indexing). js=1 waves merge into
//                 js=0 via LDS; js=0 writes f32 partials pnum[jc]/pden[jc].
//   k_comb      : out = sum_jc(pnum) / sum_jc(pden), 8 partials.
//
// MFMA conventions (verified R1/R2/R4 on this problem):
//   A frag: lane&15 = m, k = (lane>>4)*8 + i ; B same per-lane k order
//   D: col = lane&15, row = (lane>>4)*4 + reg

#define NN 8192
#define IND 512
#define OUTD 256

typedef __attribute__((ext_vector_type(8))) short short8;
typedef __attribute__((ext_vector_type(4))) short short4v;
typedef __attribute__((ext_vector_type(4))) float f32x4;

static __device__ __forceinline__ short f2bf(float f) {
  return __builtin_bit_cast(short, __float2bfloat16(f));
}

extern "C" __global__ __launch_bounds__(256) void k_convert_w(
    const float* __restrict__ W, short* __restrict__ W2) {
  const int t = blockIdx.x * 256 + threadIdx.x;  // 16384 threads
  const int row = t >> 6, kb = t & 63;
  const float* src = W + row * IND + kb * 8;
  f32x4 x0 = *(const f32x4*)src;
  f32x4 x1 = *(const f32x4*)(src + 4);
  short8 o;
  o[0] = f2bf(x0[0]); o[1] = f2bf(x0[1]); o[2] = f2bf(x0[2]); o[3] = f2bf(x0[3]);
  o[4] = f2bf(x1[0]); o[5] = f2bf(x1[1]); o[6] = f2bf(x1[2]); o[7] = f2bf(x1[3]);
  *(short8*)(W2 + (size_t)kb * 2048 + row * 8) = o;
}

extern "C" __global__ __launch_bounds__(128) void k_wh(
    const float* __restrict__ nodes, const short* __restrict__ W2,
    const float* __restrict__ Wb, const float* __restrict__ a1w,
    const float* __restrict__ a1b, const float* __restrict__ a2w,
    const float* __restrict__ a2b, short* __restrict__ WhL,
    float* __restrict__ s1, float* __restrict__ s2) {
  const int tid = threadIdx.x;
  const int wv = tid >> 6, lane = tid & 63, g = lane >> 4, m = lane & 15;
  const int rowbase = blockIdx.x * 32 + wv * 16;

  f32x4 acc[16];
#pragma unroll
  for (int nf = 0; nf < 16; ++nf) acc[nf] = (f32x4){0.f, 0.f, 0.f, 0.f};

  const float* arow = nodes + (size_t)(rowbase + m) * IND;
  const short* bb = W2 + (size_t)g * 2048 + m * 8;
#pragma unroll 4
  for (int k0 = 0; k0 < IND; k0 += 32) {
    const float* ap = arow + k0 + g * 8;
    f32x4 x0 = *(const f32x4*)ap;
    f32x4 x1 = *(const f32x4*)(ap + 4);
    short8 af;
    af[0] = f2bf(x0[0]); af[1] = f2bf(x0[1]); af[2] = f2bf(x0[2]); af[3] = f2bf(x0[3]);
    af[4] = f2bf(x1[0]); af[5] = f2bf(x1[1]); af[6] = f2bf(x1[2]); af[7] = f2bf(x1[3]);
    const short* bk = bb + (size_t)(k0 >> 3) * 2048;
#pragma unroll
    for (int nf = 0; nf < 16; ++nf) {
      short8 bf = *(const short8*)(bk + nf * 128);
      acc[nf] = __builtin_amdgcn_mfma_f32_16x16x32_bf16(af, bf, acc[nf], 0, 0, 0);
    }
  }

  float p1[4] = {0.f, 0.f, 0.f, 0.f}, p2[4] = {0.f, 0.f, 0.f, 0.f};
#pragma unroll
  for (int nf = 0; nf < 16; ++nf) {
    const int n = nf * 16 + m;
    const float b = Wb[n], c1 = a1w[n], c2 = a2w[n];
#pragma unroll
    for (int r = 0; r < 4; ++r) {
      float v = acc[nf][r] + b;
      acc[nf][r] = v;
      p1[r] += c1 * v;
      p2[r] += c2 * v;
    }
  }
#pragma unroll
  for (int off = 1; off < 16; off <<= 1) {
#pragma unroll
    for (int r = 0; r < 4; ++r) {
      p1[r] += __shfl_xor(p1[r], off);
      p2[r] += __shfl_xor(p2[r], off);
    }
  }
  if (m == 0) {
    const float b1 = a1b[0], b2 = a2b[0];
#pragma unroll
    for (int r = 0; r < 4; ++r) {
      const int row = rowbase + g * 4 + r;
      s1[row] = p1[r] + b1;
      s2[row] = p2[r] + b2;
    }
  }

  const size_t cbase = ((size_t)(rowbase >> 3) + (g >> 1)) * 2048 + (g & 1) * 4;
#pragma unroll
  for (int nf = 0; nf < 16; ++nf) {
    short4v o;
#pragma unroll
    for (int r = 0; r < 4; ++r) o[r] = f2bf(acc[nf][r]);
    *(short4v*)(WhL + cbase + (size_t)(nf * 16 + m) * 8) = o;
  }
}

// int32 mask -> bitmask. bm[row*256 + wj] bit b = mask[row][wj*32+b] != 0.
extern "C" __global__ __launch_bounds__(256) void k_mask(
    const int* __restrict__ mask, uint32_t* __restrict__ bm) {
  const int tid = threadIdx.x;
  const int wv = tid >> 6, lane = tid & 63;
  const int gw = blockIdx.x * 4 + wv;           // 4096 waves
  const size_t base = (size_t)gw * 16384;       // 64 iters x 256 ints
#pragma unroll 4
  for (int it = 0; it < 64; ++it) {
    const size_t ib = base + (size_t)it * 256;
    unsigned long long b0 = __ballot(mask[ib + lane] != 0);
    unsigned long long b1 = __ballot(mask[ib + 64 + lane] != 0);
    unsigned long long b2 = __ballot(mask[ib + 128 + lane] != 0);
    unsigned long long b3 = __ballot(mask[ib + 192 + lane] != 0);
    if (lane < 8) {
      unsigned long long s01 = (lane & 2) ? b1 : b0;
      unsigned long long s23 = (lane & 2) ? b3 : b2;
      unsigned long long sel = (lane & 4) ? s23 : s01;
      bm[ib / 32 + lane] = (uint32_t)(sel >> ((lane & 1) * 32));
    }
  }
}

extern "C" __global__ __launch_bounds__(512, 2) void k_attn(
    const uint32_t* __restrict__ bm, const short* __restrict__ WhL,
    const float* __restrict__ s1, const float* __restrict__ s2,
    float* __restrict__ pnum, float* __restrict__ pden) {
  __shared__ f32x4 cbuf[4][64][16];   // 64 KiB, js-combine buffer
  __shared__ float dbuf[4][2][16];    // den halves from js=1 waves

  const int tid = threadIdx.x;
  const int w = tid >> 6, lane = tid & 63, g = lane >> 4, m = lane & 15;
  const int rt = blockIdx.x >> 3, jc = blockIdx.x & 7;
  const int rg = w >> 1, js = w & 1;
  const int rowbase = rt * 128 + rg * 32;
  const int jbase = jc * 1024 + js * 512;

  const float s1a = s1[rowbase + m];
  const float s1b = s1[rowbase + 16 + m];

  f32x4 acc0[16], acc1[16];
#pragma unroll
  for (int nf = 0; nf < 16; ++nf) {
    acc0[nf] = (f32x4){0.f, 0.f, 0.f, 0.f};
    acc1[nf] = (f32x4){0.f, 0.f, 0.f, 0.f};
  }
  float den0 = 0.f, den1 = 0.f;

  const uint32_t* bw0 = bm + (size_t)(rowbase + m) * 256 + (jbase >> 5);
  const uint32_t* bw1 = bw0 + (size_t)16 * 256;
  const float* sp = s2 + jbase + g * 8;
  const short* bb = WhL + ((size_t)(jbase >> 3) + g) * 2048 + (size_t)m * 8;

  auto build = [&](float s1h, uint32_t bits, const f32x4& slo, const f32x4& shi,
                   float& den) -> short8 {
    short8 af;
#pragma unroll
    for (int i = 0; i < 8; ++i) {
      float sv = s1h + (i < 4 ? slo[i] : shi[i - 4]);
      sv = fmaxf(sv, 0.2f * sv);  // leaky-relu
      float pv = (bits & (1u << i)) ? __expf(sv) : 0.f;
      den += pv;
      af[i] = f2bf(pv);
    }
    return af;
  };

  // ---- 2-step register ping-pong (static indexing throughout) ----
  uint32_t wA0 = bw0[0], wA1 = bw1[0];
  f32x4 sA0 = *(const f32x4*)sp, sA1 = *(const f32x4*)(sp + 4);
  short8 Ba[16], Bb[16];
#pragma unroll
  for (int nf = 0; nf < 16; ++nf) Ba[nf] = *(const short8*)(bb + nf * 128);

  for (int u = 0; u < 16; u += 2) {
    // prefetch u+1 state (u+1 <= 15 always)
    uint32_t wB0 = bw0[u + 1], wB1 = bw1[u + 1];
    f32x4 sB0 = *(const f32x4*)(sp + (u + 1) * 32);
    f32x4 sB1 = *(const f32x4*)(sp + (u + 1) * 32 + 4);
    {
      const short* bn = bb + (size_t)(u + 1) * 8192;
#pragma unroll
      for (int nf = 0; nf < 16; ++nf) Bb[nf] = *(const short8*)(bn + nf * 128);
    }
    // compute step u with A-state
    {
      short8 af0 = build(s1a, wA0 >> (g * 8), sA0, sA1, den0);
      short8 af1 = build(s1b, wA1 >> (g * 8), sA0, sA1, den1);
#pragma unroll
      for (int nf = 0; nf < 16; ++nf) {
        acc0[nf] = __builtin_amdgcn_mfma_f32_16x16x32_bf16(af0, Ba[nf], acc0[nf], 0, 0, 0);
        acc1[nf] = __builtin_amdgcn_mfma_f32_16x16x32_bf16(af1, Ba[nf], acc1[nf], 0, 0, 0);
      }
    }
    // prefetch u+2 state (clamped; redundant loads on final iteration)
    const int u2 = (u + 2 < 16) ? (u + 2) : 15;
    wA0 = bw0[u2]; wA1 = bw1[u2];
    sA0 = *(const f32x4*)(sp + u2 * 32);
    sA1 = *(const f32x4*)(sp + u2 * 32 + 4);
    {
      const short* bn = bb + (size_t)u2 * 8192;
#pragma unroll
      for (int nf = 0; nf < 16; ++nf) Ba[nf] = *(const short8*)(bn + nf * 128);
    }
    // compute step u+1 with B-state
    {
      short8 af0 = build(s1a, wB0 >> (g * 8), sB0, sB1, den0);
      short8 af1 = build(s1b, wB1 >> (g * 8), sB0, sB1, den1);
#pragma unroll
      for (int nf = 0; nf < 16; ++nf) {
        acc0[nf] = __builtin_amdgcn_mfma_f32_16x16x32_bf16(af0, Bb[nf], acc0[nf], 0, 0, 0);
        acc1[nf] = __builtin_amdgcn_mfma_f32_16x16x32_bf16(af1, Bb[nf], acc1[nf], 0, 0, 0);
      }
    }
  }

  // per-wave den reduction: every lane ends holding den for row (lane&15)
  den0 += __shfl_xor(den0, 16); den0 += __shfl_xor(den0, 32);
  den1 += __shfl_xor(den1, 16); den1 += __shfl_xor(den1, 32);

  // js-combine: odd waves (js=1) hand acc/den to even waves (js=0)
  __syncthreads();
  if (js) {
#pragma unroll
    for (int nf = 0; nf < 16; ++nf) cbuf[rg][lane][nf ^ (lane & 7)] = acc0[nf];
    if (lane < 16) { dbuf[rg][0][m] = den0; dbuf[rg][1][m] = den1; }
  }
  __syncthreads();
  if (!js) {
#pragma unroll
    for (int nf = 0; nf < 16; ++nf) acc0[nf] += cbuf[rg][lane][nf ^ (lane & 7)];
    den0 += dbuf[rg][0][m];
    den1 += dbuf[rg][1][m];
  }
  __syncthreads();
  if (js) {
#pragma unroll
    for (int nf = 0; nf < 16; ++nf) cbuf[rg][lane][nf ^ (lane & 7)] = acc1[nf];
  }
  __syncthreads();
  if (js) return;

#pragma unroll
  for (int nf = 0; nf < 16; ++nf) acc1[nf] += cbuf[rg][lane][nf ^ (lane & 7)];

  if (lane < 16) {
    pden[jc * NN + rowbase + m] = den0;
    pden[jc * NN + rowbase + 16 + m] = den1;
  }

  float* pn = pnum + (size_t)jc * NN * OUTD;
#pragma unroll
  for (int r = 0; r < 4; ++r) {
    const int q = g * 4 + r;
    const size_t r0 = (size_t)(rowbase + q) * OUTD;
    const size_t r1 = (size_t)(rowbase + 16 + q) * OUTD;
#pragma unroll
    for (int nf = 0; nf < 16; ++nf) {
      pn[r0 + nf * 16 + m] = acc0[nf][r];
      pn[r1 + nf * 16 + m] = acc1[nf][r];
    }
  }
}

extern "C" __global__ __launch_bounds__(256) void k_comb(
    const float* __restrict__ pnum, const float* __restrict__ pden,
    float* __restrict__ out) {
  const int idx = blockIdx.x * 256 + threadIdx.x;  // 524288 threads
  const int row = idx >> 6, c4 = (idx & 63) * 4;
  f32x4 s = (f32x4){0.f, 0.f, 0.f, 0.f};
  float d = 0.f;
#pragma unroll
  for (int jc = 0; jc < 8; ++jc) {
    f32x4 v = *(const f32x4*)(pnum + ((size_t)jc * NN + row) * OUTD + c4);
    s += v;
    d += pden[jc * NN + row];
  }
  const float inv = 1.f / d;
  *(f32x4*)(out + (size_t)row * OUTD + c4) = s * inv;
}

extern "C" void kernel_launch(void* const* d_in, const int* in_sizes, int n_in,
                              void* d_out, int out_size, void* d_ws, size_t ws_size,
                              hipStream_t stream) {
  const float* nodes = (const float*)d_in[0];
  const int*   mask  = (const int*)d_in[1];
  const float* W_w   = (const float*)d_in[2];
  const float* W_b   = (const float*)d_in[3];
  const float* a1w   = (const float*)d_in[4];
  const float* a1b   = (const float*)d_in[5];
  const float* a2w   = (const float*)d_in[6];
  const float* a2b   = (const float*)d_in[7];
  float* out = (float*)d_out;

  char* ws = (char*)d_ws;
  short*    WhL  = (short*)(ws);                                  // 4 MiB
  float*    s1   = (float*)(ws + (size_t)4  * 1024 * 1024);       // 32 KiB
  float*    s2   = (float*)(ws + (size_t)4  * 1024 * 1024 + 32768);
  short*    W2   = (short*)(ws + (size_t)4  * 1024 * 1024 + 65536); // 256 KiB
  uint32_t* bmp  = (uint32_t*)(ws + (size_t)5  * 1024 * 1024);    // 8 MiB
  float*    pnum = (float*)(ws + (size_t)16 * 1024 * 1024);       // 64 MiB
  float*    pden = (float*)(ws + (size_t)96 * 1024 * 1024);       // 256 KiB

  hipLaunchKernelGGL(k_convert_w, dim3(64), dim3(256), 0, stream, W_w, W2);
  hipLaunchKernelGGL(k_wh, dim3(256), dim3(128), 0, stream,
                     nodes, W2, W_b, a1w, a1b, a2w, a2b, WhL, s1, s2);
  hipLaunchKernelGGL(k_mask, dim3(1024), dim3(256), 0, stream, mask, bmp);
  hipLaunchKernelGGL(k_attn, dim3(512), dim3(512), 0, stream,
                     bmp, WhL, s1, s2, pnum, pden);
  hipLaunchKernelGGL(k_comb, dim3(2048), dim3(256), 0, stream,
                     pnum, pden, out);
}

// Round 6
// 191.708 us; speedup vs baseline: 1.5483x; 1.5483x over previous
//
#include <hip/hip_runtime.h>
#include <hip/hip_bf16.h>
#include <stdint.h>

// DenseGraphAttentionHead N=8192, IN=512, OUT=256, ~50% dense int32 mask.
//
// Pipeline:
//   k_convert_w : W f32 -> bf16 chunked (16B chunk (kb,row) at kb*2048+row*8).
//   k_wh        : Wh = nodes@W^T + b (mfma 16x16x32 bf16) -> WhL chunked bf16
//                 (chunk (jb,n) at jb*2048+n*8), s1/s2 f32 from f32 acc.
//   k_mask      : int32 mask (268 MB, the irreducible HBM stream) -> bitmask
//                 bm[row][wj] (8.4 MB) via __ballot. Pure streaming kernel.
//   k_attn      : fused masked-softmax @ Wh on the BITMASK.
//                 Grid = 64 rt x 8 jc = 512 blocks; block = 512 thr = 8 waves
//                 = 4 rowgroups(32 rows) x 2 col-halves(128). Each wave owns a
//                 DISJOINT 32x128 output tile: acc = 64 AGPR, no combine.
//                 launch_bounds(512,4) -> <=128 regs -> 2 blocks/CU (16 w/CU).
//                 WhL j-slice (32j x 256n = 16 KB) double-buffered in LDS,
//                 T14 staging: issue glb loads u+1 -> compute u (ds_read_b128
//                 B-frags, in-reg P build, 16 MFMA) -> ds_write -> barrier.
//   k_comb      : out = sum_jc(pnum) / sum_jc(pden), 8 partials.
//
// MFMA conventions (verified R1-R5 on this problem):
//   A frag: lane&15 = m, k = (lane>>4)*8 + i ; B same per-lane k order
//   D: col = lane&15, row = (lane>>4)*4 + reg

#define NN 8192
#define IND 512
#define OUTD 256

typedef __attribute__((ext_vector_type(8))) short short8;
typedef __attribute__((ext_vector_type(4))) short short4v;
typedef __attribute__((ext_vector_type(4))) float f32x4;

static __device__ __forceinline__ short f2bf(float f) {
  return __builtin_bit_cast(short, __float2bfloat16(f));
}

extern "C" __global__ __launch_bounds__(256) void k_convert_w(
    const float* __restrict__ W, short* __restrict__ W2) {
  const int t = blockIdx.x * 256 + threadIdx.x;  // 16384 threads
  const int row = t >> 6, kb = t & 63;
  const float* src = W + row * IND + kb * 8;
  f32x4 x0 = *(const f32x4*)src;
  f32x4 x1 = *(const f32x4*)(src + 4);
  short8 o;
  o[0] = f2bf(x0[0]); o[1] = f2bf(x0[1]); o[2] = f2bf(x0[2]); o[3] = f2bf(x0[3]);
  o[4] = f2bf(x1[0]); o[5] = f2bf(x1[1]); o[6] = f2bf(x1[2]); o[7] = f2bf(x1[3]);
  *(short8*)(W2 + (size_t)kb * 2048 + row * 8) = o;
}

extern "C" __global__ __launch_bounds__(128) void k_wh(
    const float* __restrict__ nodes, const short* __restrict__ W2,
    const float* __restrict__ Wb, const float* __restrict__ a1w,
    const float* __restrict__ a1b, const float* __restrict__ a2w,
    const float* __restrict__ a2b, short* __restrict__ WhL,
    float* __restrict__ s1, float* __restrict__ s2) {
  const int tid = threadIdx.x;
  const int wv = tid >> 6, lane = tid & 63, g = lane >> 4, m = lane & 15;
  const int rowbase = blockIdx.x * 32 + wv * 16;

  f32x4 acc[16];
#pragma unroll
  for (int nf = 0; nf < 16; ++nf) acc[nf] = (f32x4){0.f, 0.f, 0.f, 0.f};

  const float* arow = nodes + (size_t)(rowbase + m) * IND;
  const short* bb = W2 + (size_t)g * 2048 + m * 8;
#pragma unroll 4
  for (int k0 = 0; k0 < IND; k0 += 32) {
    const float* ap = arow + k0 + g * 8;
    f32x4 x0 = *(const f32x4*)ap;
    f32x4 x1 = *(const f32x4*)(ap + 4);
    short8 af;
    af[0] = f2bf(x0[0]); af[1] = f2bf(x0[1]); af[2] = f2bf(x0[2]); af[3] = f2bf(x0[3]);
    af[4] = f2bf(x1[0]); af[5] = f2bf(x1[1]); af[6] = f2bf(x1[2]); af[7] = f2bf(x1[3]);
    const short* bk = bb + (size_t)(k0 >> 3) * 2048;
#pragma unroll
    for (int nf = 0; nf < 16; ++nf) {
      short8 bf = *(const short8*)(bk + nf * 128);
      acc[nf] = __builtin_amdgcn_mfma_f32_16x16x32_bf16(af, bf, acc[nf], 0, 0, 0);
    }
  }

  float p1[4] = {0.f, 0.f, 0.f, 0.f}, p2[4] = {0.f, 0.f, 0.f, 0.f};
#pragma unroll
  for (int nf = 0; nf < 16; ++nf) {
    const int n = nf * 16 + m;
    const float b = Wb[n], c1 = a1w[n], c2 = a2w[n];
#pragma unroll
    for (int r = 0; r < 4; ++r) {
      float v = acc[nf][r] + b;
      acc[nf][r] = v;
      p1[r] += c1 * v;
      p2[r] += c2 * v;
    }
  }
#pragma unroll
  for (int off = 1; off < 16; off <<= 1) {
#pragma unroll
    for (int r = 0; r < 4; ++r) {
      p1[r] += __shfl_xor(p1[r], off);
      p2[r] += __shfl_xor(p2[r], off);
    }
  }
  if (m == 0) {
    const float b1 = a1b[0], b2 = a2b[0];
#pragma unroll
    for (int r = 0; r < 4; ++r) {
      const int row = rowbase + g * 4 + r;
      s1[row] = p1[r] + b1;
      s2[row] = p2[r] + b2;
    }
  }

  const size_t cbase = ((size_t)(rowbase >> 3) + (g >> 1)) * 2048 + (g & 1) * 4;
#pragma unroll
  for (int nf = 0; nf < 16; ++nf) {
    short4v o;
#pragma unroll
    for (int r = 0; r < 4; ++r) o[r] = f2bf(acc[nf][r]);
    *(short4v*)(WhL + cbase + (size_t)(nf * 16 + m) * 8) = o;
  }
}

// int32 mask -> bitmask. bm[row*256 + wj] bit b = mask[row][wj*32+b] != 0.
extern "C" __global__ __launch_bounds__(256) void k_mask(
    const int* __restrict__ mask, uint32_t* __restrict__ bm) {
  const int tid = threadIdx.x;
  const int wv = tid >> 6, lane = tid & 63;
  const int gw = blockIdx.x * 4 + wv;           // 4096 waves
  const size_t base = (size_t)gw * 16384;       // 64 iters x 256 ints
#pragma unroll 4
  for (int it = 0; it < 64; ++it) {
    const size_t ib = base + (size_t)it * 256;
    unsigned long long b0 = __ballot(mask[ib + lane] != 0);
    unsigned long long b1 = __ballot(mask[ib + 64 + lane] != 0);
    unsigned long long b2 = __ballot(mask[ib + 128 + lane] != 0);
    unsigned long long b3 = __ballot(mask[ib + 192 + lane] != 0);
    if (lane < 8) {
      unsigned long long s01 = (lane & 2) ? b1 : b0;
      unsigned long long s23 = (lane & 2) ? b3 : b2;
      unsigned long long sel = (lane & 4) ? s23 : s01;
      bm[ib / 32 + lane] = (uint32_t)(sel >> ((lane & 1) * 32));
    }
  }
}

extern "C" __global__ __launch_bounds__(512, 4) void k_attn(
    const uint32_t* __restrict__ bm, const short* __restrict__ WhL,
    const float* __restrict__ s1, const float* __restrict__ s2,
    float* __restrict__ pnum, float* __restrict__ pden) {
  __shared__ short Bs[2][8192];  // 2 x 16 KiB double-buffered WhL j-slice

  const int tid = threadIdx.x;
  const int w = tid >> 6, lane = tid & 63, g = lane >> 4, m = lane & 15;
  const int rt = blockIdx.x >> 3, jc = blockIdx.x & 7;
  const int rg = w & 3, ns = w >> 2;
  const int rb = rt * 128 + rg * 32;

  const float s1a = s1[rb + m];
  const float s1b = s1[rb + 16 + m];

  f32x4 acc0[8], acc1[8];
#pragma unroll
  for (int nf = 0; nf < 8; ++nf) {
    acc0[nf] = (f32x4){0.f, 0.f, 0.f, 0.f};
    acc1[nf] = (f32x4){0.f, 0.f, 0.f, 0.f};
  }
  float den0 = 0.f, den1 = 0.f;

  const uint32_t* bw0 = bm + (size_t)(rb + m) * 256 + jc * 32;  // +16*256 = row m+16
  const float* sp = s2 + jc * 1024 + g * 8;
  const short* gW = WhL + (size_t)jc * 128 * 2048 + tid * 8;  // per-thread stage src

  auto build = [&](float s1h, uint32_t bits, const f32x4& slo, const f32x4& shi,
                   float& den) -> short8 {
    short8 af;
#pragma unroll
    for (int i = 0; i < 8; ++i) {
      float sv = s1h + (i < 4 ? slo[i] : shi[i - 4]);
      sv = fmaxf(sv, 0.2f * sv);  // leaky-relu
      float pv = (bits & (1u << i)) ? __expf(sv) : 0.f;
      den += pv;
      af[i] = f2bf(pv);
    }
    return af;
  };

  // prologue: stage slice 0 (regs -> LDS), prefetch mask words for u=0
  short8 sg0 = *(const short8*)(gW);
  short8 sg1 = *(const short8*)(gW + 4096);
  uint32_t cw0 = bw0[0], cw1 = bw0[16 * 256];
  *(short8*)(&Bs[0][tid * 8]) = sg0;
  *(short8*)(&Bs[0][4096 + tid * 8]) = sg1;
  __syncthreads();

  for (int u = 0; u < 32; ++u) {
    // 1. issue next-slice global loads into regs (latency hides under compute)
    if (u < 31) {
      sg0 = *(const short8*)(gW + (size_t)(u + 1) * 8192);
      sg1 = *(const short8*)(gW + (size_t)(u + 1) * 8192 + 4096);
    }
    // 2. prefetch next mask words (1-deep)
    const int un = (u < 31) ? u + 1 : 31;
    const uint32_t nw0 = bw0[un], nw1 = bw0[16 * 256 + un];

    // 3. compute step u: s2 JIT (L1-hot), P build, B-frags from LDS, 16 MFMA
    const f32x4 cs0 = *(const f32x4*)(sp + u * 32);
    const f32x4 cs1 = *(const f32x4*)(sp + u * 32 + 4);
    short8 af0 = build(s1a, cw0 >> (g * 8), cs0, cs1, den0);
    short8 af1 = build(s1b, cw1 >> (g * 8), cs0, cs1, den1);
    const short* bl = &Bs[u & 1][g * 2048 + (ns * 128 + m) * 8];
#pragma unroll
    for (int nf = 0; nf < 8; ++nf) {
      short8 bf = *(const short8*)(bl + nf * 128);
      acc0[nf] = __builtin_amdgcn_mfma_f32_16x16x32_bf16(af0, bf, acc0[nf], 0, 0, 0);
      acc1[nf] = __builtin_amdgcn_mfma_f32_16x16x32_bf16(af1, bf, acc1[nf], 0, 0, 0);
    }
    // 4. land staged regs into the other LDS buffer
    if (u < 31) {
      *(short8*)(&Bs[(u + 1) & 1][tid * 8]) = sg0;
      *(short8*)(&Bs[(u + 1) & 1][4096 + tid * 8]) = sg1;
    }
    cw0 = nw0; cw1 = nw1;
    // 5. single barrier per step
    __syncthreads();
  }

  // den reduce across the 4 k-groups: all lanes end with den for row (lane&15)
  den0 += __shfl_xor(den0, 16); den0 += __shfl_xor(den0, 32);
  den1 += __shfl_xor(den1, 16); den1 += __shfl_xor(den1, 32);
  if (ns == 0 && lane < 16) {
    pden[jc * NN + rb + m] = den0;
    pden[jc * NN + rb + 16 + m] = den1;
  }

  // each wave owns its disjoint 32x128 tile of pnum[jc]
  float* pn = pnum + (size_t)jc * NN * OUTD + (size_t)rb * OUTD + ns * 128;
#pragma unroll
  for (int r = 0; r < 4; ++r) {
    const int q = g * 4 + r;
#pragma unroll
    for (int nf = 0; nf < 8; ++nf) {
      pn[(size_t)q * OUTD + nf * 16 + m] = acc0[nf][r];
      pn[(size_t)(16 + q) * OUTD + nf * 16 + m] = acc1[nf][r];
    }
  }
}

extern "C" __global__ __launch_bounds__(256) void k_comb(
    const float* __restrict__ pnum, const float* __restrict__ pden,
    float* __restrict__ out) {
  const int idx = blockIdx.x * 256 + threadIdx.x;  // 524288 threads
  const int row = idx >> 6, c4 = (idx & 63) * 4;
  f32x4 s = (f32x4){0.f, 0.f, 0.f, 0.f};
  float d = 0.f;
#pragma unroll
  for (int jc = 0; jc < 8; ++jc) {
    f32x4 v = *(const f32x4*)(pnum + ((size_t)jc * NN + row) * OUTD + c4);
    s += v;
    d += pden[jc * NN + row];
  }
  const float inv = 1.f / d;
  *(f32x4*)(out + (size_t)row * OUTD + c4) = s * inv;
}

extern "C" void kernel_launch(void* const* d_in, const int* in_sizes, int n_in,
                              void* d_out, int out_size, void* d_ws, size_t ws_size,
                              hipStream_t stream) {
  const float* nodes = (const float*)d_in[0];
  const int*   mask  = (const int*)d_in[1];
  const float* W_w   = (const float*)d_in[2];
  const float* W_b   = (const float*)d_in[3];
  const float* a1w   = (const float*)d_in[4];
  const float* a1b   = (const float*)d_in[5];
  const float* a2w   = (const float*)d_in[6];
  const float* a2b   = (const float*)d_in[7];
  float* out = (float*)d_out;

  char* ws = (char*)d_ws;
  short*    WhL  = (short*)(ws);                                  // 4 MiB
  float*    s1   = (float*)(ws + (size_t)4  * 1024 * 1024);       // 32 KiB
  float*    s2   = (float*)(ws + (size_t)4  * 1024 * 1024 + 32768);
  short*    W2   = (short*)(ws + (size_t)4  * 1024 * 1024 + 65536); // 256 KiB
  uint32_t* bmp  = (uint32_t*)(ws + (size_t)5  * 1024 * 1024);    // 8 MiB
  float*    pnum = (float*)(ws + (size_t)16 * 1024 * 1024);       // 64 MiB
  float*    pden = (float*)(ws + (size_t)96 * 1024 * 1024);       // 256 KiB

  hipLaunchKernelGGL(k_convert_w, dim3(64), dim3(256), 0, stream, W_w, W2);
  hipLaunchKernelGGL(k_wh, dim3(256), dim3(128), 0, stream,
                     nodes, W2, W_b, a1w, a1b, a2w, a2b, WhL, s1, s2);
  hipLaunchKernelGGL(k_mask, dim3(1024), dim3(256), 0, stream, mask, bmp);
  hipLaunchKernelGGL(k_attn, dim3(512), dim3(512), 0, stream,
                     bmp, WhL, s1, s2, pnum, pden);
  hipLaunchKernelGGL(k_comb, dim3(2048), dim3(256), 0, stream,
                     pnum, pden, out);
}

// Round 7
// 185.511 us; speedup vs baseline: 1.6000x; 1.0334x over previous
//
#include <hip/hip_runtime.h>
#include <hip/hip_bf16.h>
#include <stdint.h>

// DenseGraphAttentionHead N=8192, IN=512, OUT=256, ~50% dense int32 mask.
//
// Pipeline:
//   k_convert_w : W f32 -> bf16 chunked (16B chunk (kb,row) at kb*2048+row*8).
//   k_wh        : Wh = nodes@W^T + b (mfma 16x16x32 bf16) -> WhL chunked bf16
//                 (chunk (jb,n) at jb*2048+n*8), s1/s2 f32 from f32 acc.
//   k_mask      : int32 mask (268 MB, the irreducible HBM stream) -> bitmask
//                 bm[row][wj] (8.4 MB) via __ballot. Pure streaming kernel.
//   k_attn      : fused masked-softmax @ Wh on the BITMASK.
//                 Grid = 128 rt(BM=64) x 8 jc(1024) = 1024 blocks = 4/CU
//                 (4 barrier domains/CU -> drains overlap compute).
//                 Block = 256 thr = 4 waves = 2 rowgroups(32) x 2 colhalves
//                 (128). Wave owns a DISJOINT 32x128 tile: acc = 64 AGPR,
//                 VGPR ~60 -> 4 waves/SIMD. WhL j-slice (32j x 256n = 16 KB)
//                 double-buffered in LDS via global_load_lds (async DMA, no
//                 reg round-trip), one barrier/step.
//   k_comb      : out = sum_jc(pnum) / sum_jc(pden), 8 partials.
//
// MFMA conventions (verified R1-R6 on this problem):
//   A frag: lane&15 = m, k = (lane>>4)*8 + i ; B same per-lane k order
//   D: col = lane&15, row = (lane>>4)*4 + reg

#define NN 8192
#define IND 512
#define OUTD 256

typedef __attribute__((ext_vector_type(8))) short short8;
typedef __attribute__((ext_vector_type(4))) short short4v;
typedef __attribute__((ext_vector_type(4))) float f32x4;

#define AS_GLOBAL __attribute__((address_space(1)))
#define AS_LDS __attribute__((address_space(3)))

static __device__ __forceinline__ short f2bf(float f) {
  return __builtin_bit_cast(short, __float2bfloat16(f));
}

extern "C" __global__ __launch_bounds__(256) void k_convert_w(
    const float* __restrict__ W, short* __restrict__ W2) {
  const int t = blockIdx.x * 256 + threadIdx.x;  // 16384 threads
  const int row = t >> 6, kb = t & 63;
  const float* src = W + row * IND + kb * 8;
  f32x4 x0 = *(const f32x4*)src;
  f32x4 x1 = *(const f32x4*)(src + 4);
  short8 o;
  o[0] = f2bf(x0[0]); o[1] = f2bf(x0[1]); o[2] = f2bf(x0[2]); o[3] = f2bf(x0[3]);
  o[4] = f2bf(x1[0]); o[5] = f2bf(x1[1]); o[6] = f2bf(x1[2]); o[7] = f2bf(x1[3]);
  *(short8*)(W2 + (size_t)kb * 2048 + row * 8) = o;
}

extern "C" __global__ __launch_bounds__(128) void k_wh(
    const float* __restrict__ nodes, const short* __restrict__ W2,
    const float* __restrict__ Wb, const float* __restrict__ a1w,
    const float* __restrict__ a1b, const float* __restrict__ a2w,
    const float* __restrict__ a2b, short* __restrict__ WhL,
    float* __restrict__ s1, float* __restrict__ s2) {
  const int tid = threadIdx.x;
  const int wv = tid >> 6, lane = tid & 63, g = lane >> 4, m = lane & 15;
  const int rowbase = blockIdx.x * 32 + wv * 16;

  f32x4 acc[16];
#pragma unroll
  for (int nf = 0; nf < 16; ++nf) acc[nf] = (f32x4){0.f, 0.f, 0.f, 0.f};

  const float* arow = nodes + (size_t)(rowbase + m) * IND;
  const short* bb = W2 + (size_t)g * 2048 + m * 8;
#pragma unroll 4
  for (int k0 = 0; k0 < IND; k0 += 32) {
    const float* ap = arow + k0 + g * 8;
    f32x4 x0 = *(const f32x4*)ap;
    f32x4 x1 = *(const f32x4*)(ap + 4);
    short8 af;
    af[0] = f2bf(x0[0]); af[1] = f2bf(x0[1]); af[2] = f2bf(x0[2]); af[3] = f2bf(x0[3]);
    af[4] = f2bf(x1[0]); af[5] = f2bf(x1[1]); af[6] = f2bf(x1[2]); af[7] = f2bf(x1[3]);
    const short* bk = bb + (size_t)(k0 >> 3) * 2048;
#pragma unroll
    for (int nf = 0; nf < 16; ++nf) {
      short8 bf = *(const short8*)(bk + nf * 128);
      acc[nf] = __builtin_amdgcn_mfma_f32_16x16x32_bf16(af, bf, acc[nf], 0, 0, 0);
    }
  }

  float p1[4] = {0.f, 0.f, 0.f, 0.f}, p2[4] = {0.f, 0.f, 0.f, 0.f};
#pragma unroll
  for (int nf = 0; nf < 16; ++nf) {
    const int n = nf * 16 + m;
    const float b = Wb[n], c1 = a1w[n], c2 = a2w[n];
#pragma unroll
    for (int r = 0; r < 4; ++r) {
      float v = acc[nf][r] + b;
      acc[nf][r] = v;
      p1[r] += c1 * v;
      p2[r] += c2 * v;
    }
  }
#pragma unroll
  for (int off = 1; off < 16; off <<= 1) {
#pragma unroll
    for (int r = 0; r < 4; ++r) {
      p1[r] += __shfl_xor(p1[r], off);
      p2[r] += __shfl_xor(p2[r], off);
    }
  }
  if (m == 0) {
    const float b1 = a1b[0], b2 = a2b[0];
#pragma unroll
    for (int r = 0; r < 4; ++r) {
      const int row = rowbase + g * 4 + r;
      s1[row] = p1[r] + b1;
      s2[row] = p2[r] + b2;
    }
  }

  const size_t cbase = ((size_t)(rowbase >> 3) + (g >> 1)) * 2048 + (g & 1) * 4;
#pragma unroll
  for (int nf = 0; nf < 16; ++nf) {
    short4v o;
#pragma unroll
    for (int r = 0; r < 4; ++r) o[r] = f2bf(acc[nf][r]);
    *(short4v*)(WhL + cbase + (size_t)(nf * 16 + m) * 8) = o;
  }
}

// int32 mask -> bitmask. bm[row*256 + wj] bit b = mask[row][wj*32+b] != 0.
extern "C" __global__ __launch_bounds__(256) void k_mask(
    const int* __restrict__ mask, uint32_t* __restrict__ bm) {
  const int tid = threadIdx.x;
  const int wv = tid >> 6, lane = tid & 63;
  const int gw = blockIdx.x * 4 + wv;           // 4096 waves
  const size_t base = (size_t)gw * 16384;       // 64 iters x 256 ints
#pragma unroll 4
  for (int it = 0; it < 64; ++it) {
    const size_t ib = base + (size_t)it * 256;
    unsigned long long b0 = __ballot(mask[ib + lane] != 0);
    unsigned long long b1 = __ballot(mask[ib + 64 + lane] != 0);
    unsigned long long b2 = __ballot(mask[ib + 128 + lane] != 0);
    unsigned long long b3 = __ballot(mask[ib + 192 + lane] != 0);
    if (lane < 8) {
      unsigned long long s01 = (lane & 2) ? b1 : b0;
      unsigned long long s23 = (lane & 2) ? b3 : b2;
      unsigned long long sel = (lane & 4) ? s23 : s01;
      bm[ib / 32 + lane] = (uint32_t)(sel >> ((lane & 1) * 32));
    }
  }
}

extern "C" __global__ __launch_bounds__(256, 4) void k_attn(
    const uint32_t* __restrict__ bm, const short* __restrict__ WhL,
    const float* __restrict__ s1, const float* __restrict__ s2,
    float* __restrict__ pnum, float* __restrict__ pden) {
  __shared__ short Bs[2][8192];  // 2 x 16 KiB double-buffered WhL j-slice

  const int tid = threadIdx.x;
  const int w = tid >> 6, lane = tid & 63, g = lane >> 4, m = lane & 15;
  const int rt = blockIdx.x >> 3, jc = blockIdx.x & 7;
  const int rg = w & 1, ns = w >> 1;
  const int rb = rt * 64 + rg * 32;

  const float s1a = s1[rb + m];
  const float s1b = s1[rb + 16 + m];

  f32x4 acc0[8], acc1[8];
#pragma unroll
  for (int nf = 0; nf < 8; ++nf) {
    acc0[nf] = (f32x4){0.f, 0.f, 0.f, 0.f};
    acc1[nf] = (f32x4){0.f, 0.f, 0.f, 0.f};
  }
  float den0 = 0.f, den1 = 0.f;

  const uint32_t* bw0 = bm + (size_t)(rb + m) * 256 + jc * 32;
  const uint32_t* bw1 = bw0 + (size_t)16 * 256;
  const float* sp = s2 + jc * 1024 + g * 8;
  // staging source: wave w covers shorts [w*2048, w*2048+2048) of each slice
  const short* gWu = WhL + (size_t)jc * 262144 + w * 2048 + lane * 8;

  auto build = [&](float s1h, uint32_t bits, const f32x4& slo, const f32x4& shi,
                   float& den) -> short8 {
    short8 af;
#pragma unroll
    for (int i = 0; i < 8; ++i) {
      float sv = s1h + (i < 4 ? slo[i] : shi[i - 4]);
      sv = fmaxf(sv, 0.2f * sv);  // leaky-relu
      float pv = (bits & (1u << i)) ? __expf(sv) : 0.f;
      den += pv;
      af[i] = f2bf(pv);
    }
    return af;
  };

  // prologue: async-stage slice 0, prefetch mask words for u=0
#pragma unroll
  for (int c = 0; c < 4; ++c) {
    __builtin_amdgcn_global_load_lds(
        (const AS_GLOBAL void*)(gWu + c * 512),
        (AS_LDS void*)(&Bs[0][w * 2048 + c * 512]), 16, 0, 0);
  }
  uint32_t cw0 = bw0[0], cw1 = bw1[0];
  __syncthreads();

  for (int u = 0; u < 32; ++u) {
    // 1. async-stage slice u+1 into the other buffer (drained by the barrier)
    if (u < 31) {
      const short* gn = gWu + (size_t)(u + 1) * 8192;
      short* ld = &Bs[(u + 1) & 1][w * 2048];
#pragma unroll
      for (int c = 0; c < 4; ++c) {
        __builtin_amdgcn_global_load_lds(
            (const AS_GLOBAL void*)(gn + c * 512),
            (AS_LDS void*)(ld + c * 512), 16, 0, 0);
      }
    }
    // 2. prefetch next mask words (1-deep)
    const int un = (u < 31) ? u + 1 : 31;
    const uint32_t nw0 = bw0[un], nw1 = bw1[un];

    // 3. compute step u: P build in-reg, B-frags from LDS, 16 MFMA
    const f32x4 cs0 = *(const f32x4*)(sp + u * 32);
    const f32x4 cs1 = *(const f32x4*)(sp + u * 32 + 4);
    short8 af0 = build(s1a, cw0 >> (g * 8), cs0, cs1, den0);
    short8 af1 = build(s1b, cw1 >> (g * 8), cs0, cs1, den1);
    const short* bl = &Bs[u & 1][g * 2048 + (ns * 128 + m) * 8];
#pragma unroll
    for (int nf = 0; nf < 8; ++nf) {
      short8 bf = *(const short8*)(bl + nf * 128);
      acc0[nf] = __builtin_amdgcn_mfma_f32_16x16x32_bf16(af0, bf, acc0[nf], 0, 0, 0);
      acc1[nf] = __builtin_amdgcn_mfma_f32_16x16x32_bf16(af1, bf, acc1[nf], 0, 0, 0);
    }
    cw0 = nw0; cw1 = nw1;
    // 4. single barrier per step (drains the async stage + LDS reads)
    __syncthreads();
  }

  // den reduce across the 4 k-groups: all lanes end with den for row (lane&15)
  den0 += __shfl_xor(den0, 16); den0 += __shfl_xor(den0, 32);
  den1 += __shfl_xor(den1, 16); den1 += __shfl_xor(den1, 32);
  if (ns == 0 && lane < 16) {
    pden[jc * NN + rb + m] = den0;
    pden[jc * NN + rb + 16 + m] = den1;
  }

  // each wave owns its disjoint 32x128 tile of pnum[jc]
  float* pn = pnum + (size_t)jc * NN * OUTD + (size_t)rb * OUTD + ns * 128;
#pragma unroll
  for (int r = 0; r < 4; ++r) {
    const int q = g * 4 + r;
#pragma unroll
    for (int nf = 0; nf < 8; ++nf) {
      pn[(size_t)q * OUTD + nf * 16 + m] = acc0[nf][r];
      pn[(size_t)(16 + q) * OUTD + nf * 16 + m] = acc1[nf][r];
    }
  }
}

extern "C" __global__ __launch_bounds__(256) void k_comb(
    const float* __restrict__ pnum, const float* __restrict__ pden,
    float* __restrict__ out) {
  const int idx = blockIdx.x * 256 + threadIdx.x;  // 524288 threads
  const int row = idx >> 6, c4 = (idx & 63) * 4;
  f32x4 s = (f32x4){0.f, 0.f, 0.f, 0.f};
  float d = 0.f;
#pragma unroll
  for (int jc = 0; jc < 8; ++jc) {
    f32x4 v = *(const f32x4*)(pnum + ((size_t)jc * NN + row) * OUTD + c4);
    s += v;
    d += pden[jc * NN + row];
  }
  const float inv = 1.f / d;
  *(f32x4*)(out + (size_t)row * OUTD + c4) = s * inv;
}

extern "C" void kernel_launch(void* const* d_in, const int* in_sizes, int n_in,
                              void* d_out, int out_size, void* d_ws, size_t ws_size,
                              hipStream_t stream) {
  const float* nodes = (const float*)d_in[0];
  const int*   mask  = (const int*)d_in[1];
  const float* W_w   = (const float*)d_in[2];
  const float* W_b   = (const float*)d_in[3];
  const float* a1w   = (const float*)d_in[4];
  const float* a1b   = (const float*)d_in[5];
  const float* a2w   = (const float*)d_in[6];
  const float* a2b   = (const float*)d_in[7];
  float* out = (float*)d_out;

  char* ws = (char*)d_ws;
  short*    WhL  = (short*)(ws);                                  // 4 MiB
  float*    s1   = (float*)(ws + (size_t)4  * 1024 * 1024);       // 32 KiB
  float*    s2   = (float*)(ws + (size_t)4  * 1024 * 1024 + 32768);
  short*    W2   = (short*)(ws + (size_t)4  * 1024 * 1024 + 65536); // 256 KiB
  uint32_t* bmp  = (uint32_t*)(ws + (size_t)5  * 1024 * 1024);    // 8 MiB
  float*    pnum = (float*)(ws + (size_t)16 * 1024 * 1024);       // 64 MiB
  float*    pden = (float*)(ws + (size_t)96 * 1024 * 1024);       // 256 KiB

  hipLaunchKernelGGL(k_convert_w, dim3(64), dim3(256), 0, stream, W_w, W2);
  hipLaunchKernelGGL(k_wh, dim3(256), dim3(128), 0, stream,
                     nodes, W2, W_b, a1w, a1b, a2w, a2b, WhL, s1, s2);
  hipLaunchKernelGGL(k_mask, dim3(1024), dim3(256), 0, stream, mask, bmp);
  hipLaunchKernelGGL(k_attn, dim3(1024), dim3(256), 0, stream,
                     bmp, WhL, s1, s2, pnum, pden);
  hipLaunchKernelGGL(k_comb, dim3(2048), dim3(256), 0, stream,
                     pnum, pden, out);
}

// Round 8
// 177.782 us; speedup vs baseline: 1.6695x; 1.0435x over previous
//
#include <hip/hip_runtime.h>
#include <hip/hip_bf16.h>
#include <stdint.h>

// DenseGraphAttentionHead N=8192, IN=512, OUT=256, ~50% dense int32 mask.
//
// Pipeline (k_mask FIRST so its 268MB stream doesn't evict k_wh outputs):
//   k_mask      : int32 mask -> bitmask bm[row][wj] (8.4 MB) via __ballot.
//   k_convert_w : W f32 -> bf16 chunked (16B chunk (kb,row) at kb*2048+row*8).
//   k_wh        : Wh = nodes@W^T + b (mfma) -> WhL chunked bf16 + s1/s2 f32.
//   k_prep      : exp-factorization tables. lrelu lets exp() factor:
//                 P = mask * (s1+s2>0 ? e^{s1}e^{s2} : e^{.2s1}e^{.2s2}).
//                 sAC = [A=e^{s1} | C=e^{.2 s1}] f32; sPK[j] = {f32 B=e^{s2},
//                 u32 (D16hi|s2bf16lo)} 8B/j.
//   k_attn      : masked-softmax @ Wh, NO global loads and NO v_exp in the
//                 main loop: PK slice (8 KB) staged to LDS in prologue; per
//                 step the build is pure VALU on LDS-broadcast data.
//                 Grid 128rt x 8jc = 1024 blocks = 4/CU; block 256 thr =
//                 4 waves = 2 rowgroups(32) x 2 colhalves(128); acc 64 AGPR;
//                 WhL j-slice dbl-buffered via global_load_lds; 1 barrier/step.
//   k_comb      : out = sum_jc(pnum) / sum_jc(pden), 8 partials.
//
// MFMA conventions (verified R1-R7 on this problem):
//   A frag: lane&15 = m, k = (lane>>4)*8 + i ; B same per-lane k order
//   D: col = lane&15, row = (lane>>4)*4 + reg

#define NN 8192
#define IND 512
#define OUTD 256

typedef __attribute__((ext_vector_type(8))) short short8;
typedef __attribute__((ext_vector_type(4))) short short4v;
typedef __attribute__((ext_vector_type(4))) float f32x4;
typedef __attribute__((ext_vector_type(4))) unsigned int u32x4;

#define AS_GLOBAL __attribute__((address_space(1)))
#define AS_LDS __attribute__((address_space(3)))

static __device__ __forceinline__ short f2bf(float f) {
  return __builtin_bit_cast(short, __float2bfloat16(f));
}

extern "C" __global__ __launch_bounds__(256) void k_convert_w(
    const float* __restrict__ W, short* __restrict__ W2) {
  const int t = blockIdx.x * 256 + threadIdx.x;  // 16384 threads
  const int row = t >> 6, kb = t & 63;
  const float* src = W + row * IND + kb * 8;
  f32x4 x0 = *(const f32x4*)src;
  f32x4 x1 = *(const f32x4*)(src + 4);
  short8 o;
  o[0] = f2bf(x0[0]); o[1] = f2bf(x0[1]); o[2] = f2bf(x0[2]); o[3] = f2bf(x0[3]);
  o[4] = f2bf(x1[0]); o[5] = f2bf(x1[1]); o[6] = f2bf(x1[2]); o[7] = f2bf(x1[3]);
  *(short8*)(W2 + (size_t)kb * 2048 + row * 8) = o;
}

extern "C" __global__ __launch_bounds__(128) void k_wh(
    const float* __restrict__ nodes, const short* __restrict__ W2,
    const float* __restrict__ Wb, const float* __restrict__ a1w,
    const float* __restrict__ a1b, const float* __restrict__ a2w,
    const float* __restrict__ a2b, short* __restrict__ WhL,
    float* __restrict__ s1, float* __restrict__ s2) {
  const int tid = threadIdx.x;
  const int wv = tid >> 6, lane = tid & 63, g = lane >> 4, m = lane & 15;
  const int rowbase = blockIdx.x * 32 + wv * 16;

  f32x4 acc[16];
#pragma unroll
  for (int nf = 0; nf < 16; ++nf) acc[nf] = (f32x4){0.f, 0.f, 0.f, 0.f};

  const float* arow = nodes + (size_t)(rowbase + m) * IND;
  const short* bb = W2 + (size_t)g * 2048 + m * 8;
#pragma unroll 4
  for (int k0 = 0; k0 < IND; k0 += 32) {
    const float* ap = arow + k0 + g * 8;
    f32x4 x0 = *(const f32x4*)ap;
    f32x4 x1 = *(const f32x4*)(ap + 4);
    short8 af;
    af[0] = f2bf(x0[0]); af[1] = f2bf(x0[1]); af[2] = f2bf(x0[2]); af[3] = f2bf(x0[3]);
    af[4] = f2bf(x1[0]); af[5] = f2bf(x1[1]); af[6] = f2bf(x1[2]); af[7] = f2bf(x1[3]);
    const short* bk = bb + (size_t)(k0 >> 3) * 2048;
#pragma unroll
    for (int nf = 0; nf < 16; ++nf) {
      short8 bf = *(const short8*)(bk + nf * 128);
      acc[nf] = __builtin_amdgcn_mfma_f32_16x16x32_bf16(af, bf, acc[nf], 0, 0, 0);
    }
  }

  float p1[4] = {0.f, 0.f, 0.f, 0.f}, p2[4] = {0.f, 0.f, 0.f, 0.f};
#pragma unroll
  for (int nf = 0; nf < 16; ++nf) {
    const int n = nf * 16 + m;
    const float b = Wb[n], c1 = a1w[n], c2 = a2w[n];
#pragma unroll
    for (int r = 0; r < 4; ++r) {
      float v = acc[nf][r] + b;
      acc[nf][r] = v;
      p1[r] += c1 * v;
      p2[r] += c2 * v;
    }
  }
#pragma unroll
  for (int off = 1; off < 16; off <<= 1) {
#pragma unroll
    for (int r = 0; r < 4; ++r) {
      p1[r] += __shfl_xor(p1[r], off);
      p2[r] += __shfl_xor(p2[r], off);
    }
  }
  if (m == 0) {
    const float b1 = a1b[0], b2 = a2b[0];
#pragma unroll
    for (int r = 0; r < 4; ++r) {
      const int row = rowbase + g * 4 + r;
      s1[row] = p1[r] + b1;
      s2[row] = p2[r] + b2;
    }
  }

  const size_t cbase = ((size_t)(rowbase >> 3) + (g >> 1)) * 2048 + (g & 1) * 4;
#pragma unroll
  for (int nf = 0; nf < 16; ++nf) {
    short4v o;
#pragma unroll
    for (int r = 0; r < 4; ++r) o[r] = f2bf(acc[nf][r]);
    *(short4v*)(WhL + cbase + (size_t)(nf * 16 + m) * 8) = o;
  }
}

// exp-factorization tables (see header comment)
extern "C" __global__ __launch_bounds__(256) void k_prep(
    const float* __restrict__ s1, const float* __restrict__ s2,
    float* __restrict__ sAC, uint32_t* __restrict__ sPK) {
  const int i = blockIdx.x * 256 + threadIdx.x;  // 8192 threads
  const float v1 = s1[i], v2 = s2[i];
  sAC[i] = __expf(v1);
  sAC[NN + i] = __expf(0.2f * v1);
  const float B = __expf(v2), D = __expf(0.2f * v2);
  sPK[2 * i] = __builtin_bit_cast(uint32_t, B);
  sPK[2 * i + 1] =
      ((uint32_t)(uint16_t)f2bf(D) << 16) | (uint16_t)(uint16_t)f2bf(v2);
}

// int32 mask -> bitmask. bm[row*256 + wj] bit b = mask[row][wj*32+b] != 0.
extern "C" __global__ __launch_bounds__(256) void k_mask(
    const int* __restrict__ mask, uint32_t* __restrict__ bm) {
  const int tid = threadIdx.x;
  const int wv = tid >> 6, lane = tid & 63;
  const int gw = blockIdx.x * 4 + wv;           // 4096 waves
  const size_t base = (size_t)gw * 16384;       // 64 iters x 256 ints
#pragma unroll 4
  for (int it = 0; it < 64; ++it) {
    const size_t ib = base + (size_t)it * 256;
    unsigned long long b0 = __ballot(mask[ib + lane] != 0);
    unsigned long long b1 = __ballot(mask[ib + 64 + lane] != 0);
    unsigned long long b2 = __ballot(mask[ib + 128 + lane] != 0);
    unsigned long long b3 = __ballot(mask[ib + 192 + lane] != 0);
    if (lane < 8) {
      unsigned long long s01 = (lane & 2) ? b1 : b0;
      unsigned long long s23 = (lane & 2) ? b3 : b2;
      unsigned long long sel = (lane & 4) ? s23 : s01;
      bm[ib / 32 + lane] = (uint32_t)(sel >> ((lane & 1) * 32));
    }
  }
}

extern "C" __global__ __launch_bounds__(256, 4) void k_attn(
    const uint32_t* __restrict__ bm, const short* __restrict__ WhL,
    const float* __restrict__ s1, const float* __restrict__ sAC,
    const uint32_t* __restrict__ sPK,
    float* __restrict__ pnum, float* __restrict__ pden) {
  __shared__ short Bs[2][8192];     // 32 KiB dbl-buffered WhL j-slice
  __shared__ uint32_t PKs[2048];    // 8 KiB: {f32 B, u32 D16|s2bf} x 1024 j

  const int tid = threadIdx.x;
  const int w = tid >> 6, lane = tid & 63, g = lane >> 4, m = lane & 15;
  const int rt = blockIdx.x >> 3, jc = blockIdx.x & 7;
  const int rg = w & 1, ns = w >> 1;
  const int rb = rt * 64 + rg * 32;

  // per-lane row constants (rows rb+m and rb+16+m)
  const float T0 = -s1[rb + m],        T1 = -s1[rb + 16 + m];
  const float A0 = sAC[rb + m],        A1 = sAC[rb + 16 + m];
  const float C0 = sAC[NN + rb + m],   C1 = sAC[NN + rb + 16 + m];

  f32x4 acc0[8], acc1[8];
#pragma unroll
  for (int nf = 0; nf < 8; ++nf) {
    acc0[nf] = (f32x4){0.f, 0.f, 0.f, 0.f};
    acc1[nf] = (f32x4){0.f, 0.f, 0.f, 0.f};
  }
  float den0 = 0.f, den1 = 0.f;

  const uint32_t* bw0 = bm + (size_t)(rb + m) * 256 + jc * 32;
  const uint32_t* bw1 = bw0 + (size_t)16 * 256;
  const short* gWu = WhL + (size_t)jc * 262144 + w * 2048 + lane * 8;

  // prologue: stage PK slice (8 KB) + WhL slice 0 (16 KB), prefetch mask u=0
#pragma unroll
  for (int c = 0; c < 2; ++c) {
    __builtin_amdgcn_global_load_lds(
        (const AS_GLOBAL void*)((const char*)sPK + (size_t)jc * 8192 +
                                w * 2048 + c * 1024 + lane * 16),
        (AS_LDS void*)((char*)PKs + w * 2048 + c * 1024), 16, 0, 0);
  }
#pragma unroll
  for (int c = 0; c < 4; ++c) {
    __builtin_amdgcn_global_load_lds(
        (const AS_GLOBAL void*)(gWu + c * 512),
        (AS_LDS void*)(&Bs[0][w * 2048 + c * 512]), 16, 0, 0);
  }
  uint32_t cw0 = bw0[0], cw1 = bw1[0];
  __syncthreads();

  auto build = [&](float T, float A, float C, uint32_t mbits,
                   const u32x4& q0, const u32x4& q1,
                   const u32x4& q2, const u32x4& q3, float& den) -> short8 {
    const uint32_t Bv[8] = {q0[0], q0[2], q1[0], q1[2],
                            q2[0], q2[2], q3[0], q3[2]};
    const uint32_t Dv[8] = {q0[1], q0[3], q1[1], q1[3],
                            q2[1], q2[3], q3[1], q3[3]};
    short8 af;
#pragma unroll
    for (int i = 0; i < 8; ++i) {
      const float s2v = __builtin_bit_cast(float, Dv[i] << 16);
      const bool pos = s2v > T;
      const float wv = __builtin_bit_cast(float, pos ? Bv[i] : (Dv[i] & 0xFFFF0000u));
      const float a = pos ? A : C;
      const float val = wv * a;
      const float pv = ((mbits >> i) & 1u) ? val : 0.f;
      den += pv;
      af[i] = f2bf(pv);
    }
    return af;
  };

  for (int u = 0; u < 32; ++u) {
    // 1. async-stage slice u+1 into the other buffer
    if (u < 31) {
      const short* gn = gWu + (size_t)(u + 1) * 8192;
      short* ld = &Bs[(u + 1) & 1][w * 2048];
#pragma unroll
      for (int c = 0; c < 4; ++c) {
        __builtin_amdgcn_global_load_lds(
            (const AS_GLOBAL void*)(gn + c * 512),
            (AS_LDS void*)(ld + c * 512), 16, 0, 0);
      }
    }
    // 2. prefetch next mask words
    const int un = (u < 31) ? u + 1 : 31;
    const uint32_t nw0 = bw0[un], nw1 = bw1[un];

    // 3. compute step u: PK from LDS (broadcast), exp-free P build, 16 MFMA
    const uint32_t* pk = &PKs[(u * 32 + g * 8) * 2];
    const u32x4 q0 = *(const u32x4*)(pk + 0);
    const u32x4 q1 = *(const u32x4*)(pk + 4);
    const u32x4 q2 = *(const u32x4*)(pk + 8);
    const u32x4 q3 = *(const u32x4*)(pk + 12);
    short8 af0 = build(T0, A0, C0, cw0 >> (g * 8), q0, q1, q2, q3, den0);
    short8 af1 = build(T1, A1, C1, cw1 >> (g * 8), q0, q1, q2, q3, den1);
    const short* bl = &Bs[u & 1][g * 2048 + (ns * 128 + m) * 8];
#pragma unroll
    for (int nf = 0; nf < 8; ++nf) {
      short8 bf = *(const short8*)(bl + nf * 128);
      acc0[nf] = __builtin_amdgcn_mfma_f32_16x16x32_bf16(af0, bf, acc0[nf], 0, 0, 0);
      acc1[nf] = __builtin_amdgcn_mfma_f32_16x16x32_bf16(af1, bf, acc1[nf], 0, 0, 0);
    }
    cw0 = nw0; cw1 = nw1;
    // 4. single barrier per step
    __syncthreads();
  }

  den0 += __shfl_xor(den0, 16); den0 += __shfl_xor(den0, 32);
  den1 += __shfl_xor(den1, 16); den1 += __shfl_xor(den1, 32);
  if (ns == 0 && lane < 16) {
    pden[jc * NN + rb + m] = den0;
    pden[jc * NN + rb + 16 + m] = den1;
  }

  float* pn = pnum + (size_t)jc * NN * OUTD + (size_t)rb * OUTD + ns * 128;
#pragma unroll
  for (int r = 0; r < 4; ++r) {
    const int q = g * 4 + r;
#pragma unroll
    for (int nf = 0; nf < 8; ++nf) {
      pn[(size_t)q * OUTD + nf * 16 + m] = acc0[nf][r];
      pn[(size_t)(16 + q) * OUTD + nf * 16 + m] = acc1[nf][r];
    }
  }
}

extern "C" __global__ __launch_bounds__(256) void k_comb(
    const float* __restrict__ pnum, const float* __restrict__ pden,
    float* __restrict__ out) {
  const int idx = blockIdx.x * 256 + threadIdx.x;  // 524288 threads
  const int row = idx >> 6, c4 = (idx & 63) * 4;
  f32x4 s = (f32x4){0.f, 0.f, 0.f, 0.f};
  float d = 0.f;
#pragma unroll
  for (int jc = 0; jc < 8; ++jc) {
    f32x4 v = *(const f32x4*)(pnum + ((size_t)jc * NN + row) * OUTD + c4);
    s += v;
    d += pden[jc * NN + row];
  }
  const float inv = 1.f / d;
  *(f32x4*)(out + (size_t)row * OUTD + c4) = s * inv;
}

extern "C" void kernel_launch(void* const* d_in, const int* in_sizes, int n_in,
                              void* d_out, int out_size, void* d_ws, size_t ws_size,
                              hipStream_t stream) {
  const float* nodes = (const float*)d_in[0];
  const int*   mask  = (const int*)d_in[1];
  const float* W_w   = (const float*)d_in[2];
  const float* W_b   = (const float*)d_in[3];
  const float* a1w   = (const float*)d_in[4];
  const float* a1b   = (const float*)d_in[5];
  const float* a2w   = (const float*)d_in[6];
  const float* a2b   = (const float*)d_in[7];
  float* out = (float*)d_out;

  char* ws = (char*)d_ws;
  short*    WhL  = (short*)(ws);                                  // 4 MiB
  float*    s1   = (float*)(ws + (size_t)4  * 1024 * 1024);       // 32 KiB
  float*    s2   = (float*)(ws + (size_t)4  * 1024 * 1024 + 32768);
  short*    W2   = (short*)(ws + (size_t)4  * 1024 * 1024 + 65536); // 256 KiB
  uint32_t* bmp  = (uint32_t*)(ws + (size_t)5  * 1024 * 1024);    // 8 MiB
  float*    sAC  = (float*)(ws + (size_t)13 * 1024 * 1024);       // 64 KiB
  uint32_t* sPK  = (uint32_t*)(ws + (size_t)14 * 1024 * 1024);    // 64 KiB
  float*    pnum = (float*)(ws + (size_t)16 * 1024 * 1024);       // 64 MiB
  float*    pden = (float*)(ws + (size_t)96 * 1024 * 1024);       // 256 KiB

  // k_mask first: its 268MB stream runs BEFORE k_wh/k_prep write their
  // outputs, so WhL/sAC/sPK stay L2-resident for k_attn.
  hipLaunchKernelGGL(k_mask, dim3(1024), dim3(256), 0, stream, mask, bmp);
  hipLaunchKernelGGL(k_convert_w, dim3(64), dim3(256), 0, stream, W_w, W2);
  hipLaunchKernelGGL(k_wh, dim3(256), dim3(128), 0, stream,
                     nodes, W2, W_b, a1w, a1b, a2w, a2b, WhL, s1, s2);
  hipLaunchKernelGGL(k_prep, dim3(32), dim3(256), 0, stream, s1, s2, sAC, sPK);
  hipLaunchKernelGGL(k_attn, dim3(1024), dim3(256), 0, stream,
                     bmp, WhL, s1, sAC, sPK, pnum, pden);
  hipLaunchKernelGGL(k_comb, dim3(2048), dim3(256), 0, stream,
                     pnum, pden, out);
}

// Round 9
// 175.388 us; speedup vs baseline: 1.6923x; 1.0137x over previous
//
#include <hip/hip_runtime.h>
#include <hip/hip_bf16.h>
#include <stdint.h>

// DenseGraphAttentionHead N=8192, IN=512, OUT=256, ~50% dense int32 mask.
//
// Pipeline (k_mask FIRST so its 268MB stream doesn't evict later outputs):
//   k_mask      : int32 mask -> bitmask bm[row][wj] (8.4 MB) via __ballot.
//   k_convert_w : W f32 -> bf16 chunked (16B chunk (kb,row) at kb*2048+row*8).
//   k_wh        : Wh = nodes@W^T + b (mfma) -> WhL chunked bf16 + s1/s2 f32.
//   k_prep      : exp-factorization tables (lrelu lets exp factor):
//                 P = mask * (s1+s2>0 ? e^{s1}e^{s2} : e^{.2s1}e^{.2s2}).
//   k_attn      : masked-softmax @ Wh. BM=128, grid 64rt x 8jc = 512 blocks
//                 = 2/CU; 8 waves = 4 rowgroups(32) x 2 colhalves(128);
//                 acc 64 AGPR, launch_bounds(512,4) -> 16 waves/CU.
//                 3-slice LDS ring + counted s_waitcnt vmcnt(2) + raw
//                 s_barrier: slice loads issued at step u land at u+2, never
//                 drained to 0 (T4). Loop VMEM = exactly 2 global_load_lds
//                 (mask bits + PK staged to LDS in prologue; bm XOR-swizzled
//                 [row][u^(row&31)] to avoid the stride-32 bank conflict).
//   k_comb      : out = sum_jc(pnum) / sum_jc(pden), 8 partials.
//
// MFMA conventions (verified R1-R8 on this problem):
//   A frag: lane&15 = m, k = (lane>>4)*8 + i ; B same per-lane k order
//   D: col = lane&15, row = (lane>>4)*4 + reg

#define NN 8192
#define IND 512
#define OUTD 256

typedef __attribute__((ext_vector_type(8))) short short8;
typedef __attribute__((ext_vector_type(4))) short short4v;
typedef __attribute__((ext_vector_type(4))) float f32x4;
typedef __attribute__((ext_vector_type(4))) unsigned int u32x4;

#define AS_GLOBAL __attribute__((address_space(1)))
#define AS_LDS __attribute__((address_space(3)))

static __device__ __forceinline__ short f2bf(float f) {
  return __builtin_bit_cast(short, __float2bfloat16(f));
}

extern "C" __global__ __launch_bounds__(256) void k_convert_w(
    const float* __restrict__ W, short* __restrict__ W2) {
  const int t = blockIdx.x * 256 + threadIdx.x;  // 16384 threads
  const int row = t >> 6, kb = t & 63;
  const float* src = W + row * IND + kb * 8;
  f32x4 x0 = *(const f32x4*)src;
  f32x4 x1 = *(const f32x4*)(src + 4);
  short8 o;
  o[0] = f2bf(x0[0]); o[1] = f2bf(x0[1]); o[2] = f2bf(x0[2]); o[3] = f2bf(x0[3]);
  o[4] = f2bf(x1[0]); o[5] = f2bf(x1[1]); o[6] = f2bf(x1[2]); o[7] = f2bf(x1[3]);
  *(short8*)(W2 + (size_t)kb * 2048 + row * 8) = o;
}

extern "C" __global__ __launch_bounds__(128) void k_wh(
    const float* __restrict__ nodes, const short* __restrict__ W2,
    const float* __restrict__ Wb, const float* __restrict__ a1w,
    const float* __restrict__ a1b, const float* __restrict__ a2w,
    const float* __restrict__ a2b, short* __restrict__ WhL,
    float* __restrict__ s1, float* __restrict__ s2) {
  const int tid = threadIdx.x;
  const int wv = tid >> 6, lane = tid & 63, g = lane >> 4, m = lane & 15;
  const int rowbase = blockIdx.x * 32 + wv * 16;

  f32x4 acc[16];
#pragma unroll
  for (int nf = 0; nf < 16; ++nf) acc[nf] = (f32x4){0.f, 0.f, 0.f, 0.f};

  const float* arow = nodes + (size_t)(rowbase + m) * IND;
  const short* bb = W2 + (size_t)g * 2048 + m * 8;
#pragma unroll 4
  for (int k0 = 0; k0 < IND; k0 += 32) {
    const float* ap = arow + k0 + g * 8;
    f32x4 x0 = *(const f32x4*)ap;
    f32x4 x1 = *(const f32x4*)(ap + 4);
    short8 af;
    af[0] = f2bf(x0[0]); af[1] = f2bf(x0[1]); af[2] = f2bf(x0[2]); af[3] = f2bf(x0[3]);
    af[4] = f2bf(x1[0]); af[5] = f2bf(x1[1]); af[6] = f2bf(x1[2]); af[7] = f2bf(x1[3]);
    const short* bk = bb + (size_t)(k0 >> 3) * 2048;
#pragma unroll
    for (int nf = 0; nf < 16; ++nf) {
      short8 bf = *(const short8*)(bk + nf * 128);
      acc[nf] = __builtin_amdgcn_mfma_f32_16x16x32_bf16(af, bf, acc[nf], 0, 0, 0);
    }
  }

  float p1[4] = {0.f, 0.f, 0.f, 0.f}, p2[4] = {0.f, 0.f, 0.f, 0.f};
#pragma unroll
  for (int nf = 0; nf < 16; ++nf) {
    const int n = nf * 16 + m;
    const float b = Wb[n], c1 = a1w[n], c2 = a2w[n];
#pragma unroll
    for (int r = 0; r < 4; ++r) {
      float v = acc[nf][r] + b;
      acc[nf][r] = v;
      p1[r] += c1 * v;
      p2[r] += c2 * v;
    }
  }
#pragma unroll
  for (int off = 1; off < 16; off <<= 1) {
#pragma unroll
    for (int r = 0; r < 4; ++r) {
      p1[r] += __shfl_xor(p1[r], off);
      p2[r] += __shfl_xor(p2[r], off);
    }
  }
  if (m == 0) {
    const float b1 = a1b[0], b2 = a2b[0];
#pragma unroll
    for (int r = 0; r < 4; ++r) {
      const int row = rowbase + g * 4 + r;
      s1[row] = p1[r] + b1;
      s2[row] = p2[r] + b2;
    }
  }

  const size_t cbase = ((size_t)(rowbase >> 3) + (g >> 1)) * 2048 + (g & 1) * 4;
#pragma unroll
  for (int nf = 0; nf < 16; ++nf) {
    short4v o;
#pragma unroll
    for (int r = 0; r < 4; ++r) o[r] = f2bf(acc[nf][r]);
    *(short4v*)(WhL + cbase + (size_t)(nf * 16 + m) * 8) = o;
  }
}

// exp-factorization tables
extern "C" __global__ __launch_bounds__(256) void k_prep(
    const float* __restrict__ s1, const float* __restrict__ s2,
    float* __restrict__ sAC, uint32_t* __restrict__ sPK) {
  const int i = blockIdx.x * 256 + threadIdx.x;  // 8192 threads
  const float v1 = s1[i], v2 = s2[i];
  sAC[i] = __expf(v1);
  sAC[NN + i] = __expf(0.2f * v1);
  const float B = __expf(v2), D = __expf(0.2f * v2);
  sPK[2 * i] = __builtin_bit_cast(uint32_t, B);
  sPK[2 * i + 1] =
      ((uint32_t)(uint16_t)f2bf(D) << 16) | (uint16_t)(uint16_t)f2bf(v2);
}

// int32 mask -> bitmask. bm[row*256 + wj] bit b = mask[row][wj*32+b] != 0.
extern "C" __global__ __launch_bounds__(256) void k_mask(
    const int* __restrict__ mask, uint32_t* __restrict__ bm) {
  const int tid = threadIdx.x;
  const int wv = tid >> 6, lane = tid & 63;
  const int gw = blockIdx.x * 4 + wv;           // 4096 waves
  const size_t base = (size_t)gw * 16384;       // 64 iters x 256 ints
#pragma unroll 4
  for (int it = 0; it < 64; ++it) {
    const size_t ib = base + (size_t)it * 256;
    unsigned long long b0 = __ballot(mask[ib + lane] != 0);
    unsigned long long b1 = __ballot(mask[ib + 64 + lane] != 0);
    unsigned long long b2 = __ballot(mask[ib + 128 + lane] != 0);
    unsigned long long b3 = __ballot(mask[ib + 192 + lane] != 0);
    if (lane < 8) {
      unsigned long long s01 = (lane & 2) ? b1 : b0;
      unsigned long long s23 = (lane & 2) ? b3 : b2;
      unsigned long long sel = (lane & 4) ? s23 : s01;
      bm[ib / 32 + lane] = (uint32_t)(sel >> ((lane & 1) * 32));
    }
  }
}

extern "C" __global__ __launch_bounds__(512, 4) void k_attn(
    const uint32_t* __restrict__ bm, const short* __restrict__ WhL,
    const float* __restrict__ s1, const float* __restrict__ sAC,
    const uint32_t* __restrict__ sPK,
    float* __restrict__ pnum, float* __restrict__ pden) {
  // LDS: [0,49152) 3-slice WhL ring; [49152,57344) PK; [57344,73728) bm words
  __shared__ char smem[73728];
  uint32_t* PKs = (uint32_t*)(smem + 49152);
  uint32_t* BMs = (uint32_t*)(smem + 57344);

  const int tid = threadIdx.x;
  const int w = tid >> 6, lane = tid & 63, g = lane >> 4, m = lane & 15;
  const int rt = blockIdx.x >> 3, jc = blockIdx.x & 7;
  const int rg = w & 3, ns = w >> 2;
  const int rb = rt * 128 + rg * 32;

  // per-lane row constants (rows rb+m and rb+16+m)
  const float T0 = -s1[rb + m],        T1 = -s1[rb + 16 + m];
  const float A0 = sAC[rb + m],        A1 = sAC[rb + 16 + m];
  const float C0 = sAC[NN + rb + m],   C1 = sAC[NN + rb + 16 + m];

  f32x4 acc0[8], acc1[8];
#pragma unroll
  for (int nf = 0; nf < 8; ++nf) {
    acc0[nf] = (f32x4){0.f, 0.f, 0.f, 0.f};
    acc1[nf] = (f32x4){0.f, 0.f, 0.f, 0.f};
  }
  float den0 = 0.f, den1 = 0.f;

  // ---- prologue ----
  // bm slice (128 rows x 32 words), XOR-swizzled: word (rloc,u) at
  // BMs[rloc*32 + (u ^ (rloc & 31))]
  {
    const int rloc = tid >> 2, wq = (tid & 3) * 8;
    const uint32_t* src = bm + (size_t)(rt * 128 + rloc) * 256 + jc * 32 + wq;
    u32x4 a = *(const u32x4*)src;
    u32x4 b = *(const u32x4*)(src + 4);
#pragma unroll
    for (int i = 0; i < 4; ++i)
      BMs[rloc * 32 + ((wq + i) ^ (rloc & 31))] = a[i];
#pragma unroll
    for (int i = 0; i < 4; ++i)
      BMs[rloc * 32 + ((wq + 4 + i) ^ (rloc & 31))] = b[i];
  }
  // PK slice (8 KB)
  __builtin_amdgcn_global_load_lds(
      (const AS_GLOBAL void*)((const char*)sPK + (size_t)jc * 8192 +
                              w * 1024 + lane * 16),
      (AS_LDS void*)(smem + 49152 + w * 1024), 16, 0, 0);
  // WhL slices 0 and 1 into ring bufs 0,1
  const short* gS = WhL + (size_t)jc * 262144;
#pragma unroll
  for (int s = 0; s < 2; ++s) {
#pragma unroll
    for (int c = 0; c < 2; ++c) {
      __builtin_amdgcn_global_load_lds(
          (const AS_GLOBAL void*)(gS + s * 8192 + w * 1024 + c * 512 + lane * 8),
          (AS_LDS void*)(smem + s * 16384 + w * 2048 + c * 1024), 16, 0, 0);
    }
  }
  __syncthreads();  // drains prologue loads (vmcnt 0): slices 0,1 + PK ready

  auto build = [&](float T, float A, float C, uint32_t mbits,
                   const u32x4& q0, const u32x4& q1,
                   const u32x4& q2, const u32x4& q3, float& den) -> short8 {
    const uint32_t Bv[8] = {q0[0], q0[2], q1[0], q1[2],
                            q2[0], q2[2], q3[0], q3[2]};
    const uint32_t Dv[8] = {q0[1], q0[3], q1[1], q1[3],
                            q2[1], q2[3], q3[1], q3[3]};
    short8 af;
#pragma unroll
    for (int i = 0; i < 8; ++i) {
      const float s2v = __builtin_bit_cast(float, Dv[i] << 16);
      const bool pos = s2v > T;
      const float wv = __builtin_bit_cast(float, pos ? Bv[i] : (Dv[i] & 0xFFFF0000u));
      const float a = pos ? A : C;
      const float val = wv * a;
      const float pv = ((mbits >> i) & 1u) ? val : 0.f;
      den += pv;
      af[i] = f2bf(pv);
    }
    return af;
  };

  // ---- main loop: ring-3, counted vmcnt, one barrier/step ----
  for (int u = 0; u < 32; ++u) {
    // slice u's loads (issued at step u-2 / prologue) must be done in THIS
    // wave before entering the barrier; after the barrier all waves' are.
    asm volatile("s_waitcnt vmcnt(2)" ::: "memory");
    __builtin_amdgcn_s_barrier();
    __builtin_amdgcn_sched_barrier(0);

    // issue slice u+2 into buf[(u+2)%3] (overwrites buf[u-1]; all waves are
    // past compute u-1 because of the barrier above). Clamped re-issues at
    // u=30,31 keep the vmcnt count uniform; they land in dead buffers.
    {
      const int up = (u + 2 < 32) ? (u + 2) : 31;
      const int bi = (u + 2) % 3;
      const short* gn = gS + up * 8192 + w * 1024 + lane * 8;
      char* ldb = smem + bi * 16384 + w * 2048;
      __builtin_amdgcn_global_load_lds((const AS_GLOBAL void*)gn,
                                       (AS_LDS void*)ldb, 16, 0, 0);
      __builtin_amdgcn_global_load_lds((const AS_GLOBAL void*)(gn + 512),
                                       (AS_LDS void*)(ldb + 1024), 16, 0, 0);
    }

    // mask words + PK from LDS (conflict-free), exp-free P build, 16 MFMA
    const uint32_t cw0 = BMs[(rg * 32 + m) * 32 + (u ^ m)];
    const uint32_t cw1 = BMs[(rg * 32 + 16 + m) * 32 + (u ^ (16 + m))];
    const uint32_t* pk = &PKs[u * 64 + g * 16];
    const u32x4 q0 = *(const u32x4*)(pk + 0);
    const u32x4 q1 = *(const u32x4*)(pk + 4);
    const u32x4 q2 = *(const u32x4*)(pk + 8);
    const u32x4 q3 = *(const u32x4*)(pk + 12);
    short8 af0 = build(T0, A0, C0, cw0 >> (g * 8), q0, q1, q2, q3, den0);
    short8 af1 = build(T1, A1, C1, cw1 >> (g * 8), q0, q1, q2, q3, den1);

    const short* bl = (const short*)(smem + (u % 3) * 16384) +
                      g * 2048 + (ns * 128 + m) * 8;
#pragma unroll
    for (int nf = 0; nf < 8; ++nf) {
      short8 bf = *(const short8*)(bl + nf * 128);
      acc0[nf] = __builtin_amdgcn_mfma_f32_16x16x32_bf16(af0, bf, acc0[nf], 0, 0, 0);
      acc1[nf] = __builtin_amdgcn_mfma_f32_16x16x32_bf16(af1, bf, acc1[nf], 0, 0, 0);
    }
  }

  // den reduce across the 4 k-groups
  den0 += __shfl_xor(den0, 16); den0 += __shfl_xor(den0, 32);
  den1 += __shfl_xor(den1, 16); den1 += __shfl_xor(den1, 32);
  if (ns == 0 && lane < 16) {
    pden[jc * NN + rb + m] = den0;
    pden[jc * NN + rb + 16 + m] = den1;
  }

  // each wave owns its disjoint 32x128 tile of pnum[jc]
  float* pn = pnum + (size_t)jc * NN * OUTD + (size_t)rb * OUTD + ns * 128;
#pragma unroll
  for (int r = 0; r < 4; ++r) {
    const int q = g * 4 + r;
#pragma unroll
    for (int nf = 0; nf < 8; ++nf) {
      pn[(size_t)q * OUTD + nf * 16 + m] = acc0[nf][r];
      pn[(size_t)(16 + q) * OUTD + nf * 16 + m] = acc1[nf][r];
    }
  }
}

extern "C" __global__ __launch_bounds__(256) void k_comb(
    const float* __restrict__ pnum, const float* __restrict__ pden,
    float* __restrict__ out) {
  const int idx = blockIdx.x * 256 + threadIdx.x;  // 524288 threads
  const int row = idx >> 6, c4 = (idx & 63) * 4;
  f32x4 s = (f32x4){0.f, 0.f, 0.f, 0.f};
  float d = 0.f;
#pragma unroll
  for (int jc = 0; jc < 8; ++jc) {
    f32x4 v = *(const f32x4*)(pnum + ((size_t)jc * NN + row) * OUTD + c4);
    s += v;
    d += pden[jc * NN + row];
  }
  const float inv = 1.f / d;
  *(f32x4*)(out + (size_t)row * OUTD + c4) = s * inv;
}

extern "C" void kernel_launch(void* const* d_in, const int* in_sizes, int n_in,
                              void* d_out, int out_size, void* d_ws, size_t ws_size,
                              hipStream_t stream) {
  const float* nodes = (const float*)d_in[0];
  const int*   mask  = (const int*)d_in[1];
  const float* W_w   = (const float*)d_in[2];
  const float* W_b   = (const float*)d_in[3];
  const float* a1w   = (const float*)d_in[4];
  const float* a1b   = (const float*)d_in[5];
  const float* a2w   = (const float*)d_in[6];
  const float* a2b   = (const float*)d_in[7];
  float* out = (float*)d_out;

  char* ws = (char*)d_ws;
  short*    WhL  = (short*)(ws);                                  // 4 MiB
  float*    s1   = (float*)(ws + (size_t)4  * 1024 * 1024);       // 32 KiB
  float*    s2   = (float*)(ws + (size_t)4  * 1024 * 1024 + 32768);
  short*    W2   = (short*)(ws + (size_t)4  * 1024 * 1024 + 65536); // 256 KiB
  uint32_t* bmp  = (uint32_t*)(ws + (size_t)5  * 1024 * 1024);    // 8 MiB
  float*    sAC  = (float*)(ws + (size_t)13 * 1024 * 1024);       // 64 KiB
  uint32_t* sPK  = (uint32_t*)(ws + (size_t)14 * 1024 * 1024);    // 64 KiB
  float*    pnum = (float*)(ws + (size_t)16 * 1024 * 1024);       // 64 MiB
  float*    pden = (float*)(ws + (size_t)96 * 1024 * 1024);       // 256 KiB

  hipLaunchKernelGGL(k_mask, dim3(1024), dim3(256), 0, stream, mask, bmp);
  hipLaunchKernelGGL(k_convert_w, dim3(64), dim3(256), 0, stream, W_w, W2);
  hipLaunchKernelGGL(k_wh, dim3(256), dim3(128), 0, stream,
                     nodes, W2, W_b, a1w, a1b, a2w, a2b, WhL, s1, s2);
  hipLaunchKernelGGL(k_prep, dim3(32), dim3(256), 0, stream, s1, s2, sAC, sPK);
  hipLaunchKernelGGL(k_attn, dim3(512), dim3(512), 0, stream,
                     bmp, WhL, s1, sAC, sPK, pnum, pden);
  hipLaunchKernelGGL(k_comb, dim3(2048), dim3(256), 0, stream,
                     pnum, pden, out);
}